// Round 5
// baseline (211.283 us; speedup 1.0000x reference)
//
#include <hip/hip_runtime.h>
#include <hip/hip_bf16.h>

// Pipeline (no global atomics for data — write through to HBM per-op; r3/4).
// Gathers are at the per-XCD compulsory-miss x per-request floor (r17 fit:
// ~22us requests + ~22us bytes per 800K x 128B pass); parked. r18: layer-2
// GEMM fused into layer-1 gather. r19/r20: packed/full-range u16 hist, u16
// partial, build traffic diet (190.2us; traffic cuts returned ~nothing ->
// build is LAUNCH-GAP bound, ~6-10us per dispatch boundary).
// Round 21 (this): fuse {dinv_scan, base, bin2} into ONE k_build kernel with
// a hand-rolled grid barrier (generation arrive+spin, device-scope atomics;
// 128 blocks x 1024thr x 50KB LDS provably co-resident on 256 CUs). Barrier
// ints zeroed by dispatch 1 each replay. 6 -> 4 dispatches (-2 gaps).
// Gather kernels untouched (occupancy on the latency-bound path is king).

#define NCHUNK 32     // edge chunks
#define NRANGE_B 4    // bin2 node ranges (range = 12500)
#define HIST_B2 12544
#define SMEM1 100352  // dispatch-1 union: 25088 words (full-range u16 hist) | W frags
#define NB_BUILD (NRANGE_B * NCHUNK)   // 128 build blocks

typedef __attribute__((ext_vector_type(8))) short bfrag;   // 8 bf16 = 4 VGPRs
typedef __attribute__((ext_vector_type(4))) float f32x4;

// ---------- grid barrier: generation arrive+spin (no count reset race) ----------
__device__ __forceinline__ void gsync(int* cnt, int* gen, int nb) {
  __syncthreads();
  if (threadIdx.x == 0) {
    int my = atomicAdd(gen, 0);            // current generation (== #completed)
    __threadfence();                       // order prior writes before arrive
    int prev = atomicAdd(cnt, 1);          // monotone arrival counter
    if (prev == nb * (my + 1) - 1) {
      __threadfence();
      atomicAdd(gen, 1);                   // release
    } else {
      while (atomicAdd(gen, 0) == my) __builtin_amdgcn_s_sleep(2);
      __threadfence();
    }
  }
  __syncthreads();
}

// ---------- MFMA 16-row wave tile: t = h@Wn (opt *dinv), agg = h@Wi + bias ----------
// W LDS layout is FRAGMENT ORDER: frag (ct,kb) at shorts [((ct*2+kb)*64+lane)*8].
template <bool RELU, bool PRESCALE>
__device__ __forceinline__ void gemm_tile16(
    const float* h, const float* __restrict__ dinv,
    const short* Wn_f, const short* Wi_f, const float* b_s,
    __hip_bfloat16* __restrict__ t, float* agg, int r0, int lane, int N) {
  const int m = lane & 15;
  const int quad = lane >> 4;

  bfrag Bn[4][2], Bi[4][2];
#pragma unroll
  for (int ct = 0; ct < 4; ++ct)
#pragma unroll
    for (int kb = 0; kb < 2; ++kb) {
      Bn[ct][kb] = *(const bfrag*)&Wn_f[((ct * 2 + kb) * 64 + lane) * 8];
      Bi[ct][kb] = *(const bfrag*)&Wi_f[((ct * 2 + kb) * 64 + lane) * 8];
    }

  const int arow = r0 + m;
  bfrag A[2];
#pragma unroll
  for (int kb = 0; kb < 2; ++kb) {
    bfrag av = {};
    if (arow < N) {
      const float* src = &h[(size_t)arow * 64 + kb * 32 + quad * 8];
      float4 f0 = *(const float4*)src;
      float4 f1 = *(const float4*)(src + 4);
      float tmp[8] = {f0.x, f0.y, f0.z, f0.w, f1.x, f1.y, f1.z, f1.w};
#pragma unroll
      for (int j = 0; j < 8; ++j) {
        float v = RELU ? fmaxf(tmp[j], 0.f) : tmp[j];
        __hip_bfloat16 hb = __float2bfloat16(v);
        av[j] = *(short*)&hb;
      }
    }
    A[kb] = av;
  }

  f32x4 accT[4], accA[4];
#pragma unroll
  for (int ct = 0; ct < 4; ++ct) {
    f32x4 z = {0.f, 0.f, 0.f, 0.f};
    accT[ct] = z;
    accA[ct] = z;
  }
#pragma unroll
  for (int ct = 0; ct < 4; ++ct) {
    accT[ct] = __builtin_amdgcn_mfma_f32_16x16x32_bf16(A[0], Bn[ct][0], accT[ct], 0, 0, 0);
    accT[ct] = __builtin_amdgcn_mfma_f32_16x16x32_bf16(A[1], Bn[ct][1], accT[ct], 0, 0, 0);
    accA[ct] = __builtin_amdgcn_mfma_f32_16x16x32_bf16(A[0], Bi[ct][0], accA[ct], 0, 0, 0);
    accA[ct] = __builtin_amdgcn_mfma_f32_16x16x32_bf16(A[1], Bi[ct][1], accA[ct], 0, 0, 0);
  }

#pragma unroll
  for (int reg = 0; reg < 4; ++reg) {
    int r = r0 + quad * 4 + reg;
    if (r < N) {
      float dv = PRESCALE ? dinv[r] : 1.0f;
#pragma unroll
      for (int ct = 0; ct < 4; ++ct) {
        int col = ct * 16 + m;
        float tv = PRESCALE ? accT[ct][reg] * dv : accT[ct][reg];
        t[(size_t)r * 64 + col] = __float2bfloat16(tv);
        agg[(size_t)r * 64 + col] = accA[ct][reg] + b_s[col];
      }
    }
  }
}

// W staging in fragment order (256 or 1024 threads)
__device__ __forceinline__ void stage_W_frag(const float* __restrict__ Wn,
                                             const float* __restrict__ Wi,
                                             short* Wn_f, short* Wi_f,
                                             int tid, int nthr) {
  for (int i = tid; i < 4096; i += nthr) {
    int k = i >> 6, n = i & 63;
    int dst = (((n >> 4) * 2 + (k >> 5)) * 64 + ((k >> 3) & 3) * 16 + (n & 15)) * 8 + (k & 7);
    __hip_bfloat16 a = __float2bfloat16(Wn[i]);
    __hip_bfloat16 b = __float2bfloat16(Wi[i]);
    Wn_f[dst] = *(short*)&a;
    Wi_f[dst] = *(short*)&b;
  }
}

// ---------- FUSED dispatch 1: layer-1 GEMM blocks + full-range u16 histogram ----------
__global__ __launch_bounds__(1024) void k_hist_gemm1(
    const int* __restrict__ ei, unsigned short* __restrict__ partial,
    const float* __restrict__ x,
    const float* __restrict__ Wn, const float* __restrict__ Wi,
    const float* __restrict__ bias,
    __hip_bfloat16* __restrict__ t, float* __restrict__ agg,
    int* __restrict__ bars,
    int N, int E, int gemmBlocks) {
  __shared__ __align__(16) char smem[SMEM1];   // union: u16 hist | W frags
  const int tid = threadIdx.x;

  if ((int)blockIdx.x < gemmBlocks) {
    short* Wn_f = (short*)smem;                     // 8192 B
    short* Wi_f = (short*)(smem + 8192);            // 8192 B
    float* b_s = (float*)(smem + 16384);            // 256 B
    stage_W_frag(Wn, Wi, Wn_f, Wi_f, tid, 1024);
    if (tid < 64) b_s[tid] = bias[tid];
    __syncthreads();
    int w = tid >> 6;
    int lane = tid & 63;
    int r0 = blockIdx.x * 256 + w * 16;
    gemm_tile16<false, false>(x, nullptr, Wn_f, Wi_f, b_s, t, agg, r0, lane, N);
    return;
  }

  int* histw = (int*)smem;
  int bid = blockIdx.x - gemmBlocks;
  if (bid == 0 && tid < 4) bars[tid] = 0;   // arm k_build's grid barrier
  int c = bid % NCHUNK;
  int a = bid / NCHUNK;
  const int* ids = ei + (size_t)a * E;
  const int sw = (N + 1) & ~1;      // even u16 stride
  const int words = sw >> 1;
  for (int i = tid; i < words; i += 1024) histw[i] = 0;
  __syncthreads();
  int e0 = (int)((long long)E * c / NCHUNK);
  int e1 = (int)((long long)E * (c + 1) / NCHUNK);
  for (int e = e0 + tid; e < e1; e += 1024) {
    int s = ids[e];
    atomicAdd(&histw[s >> 1], 1 << ((s & 1) * 16));  // LDS atomic, packed u16
  }
  __syncthreads();
  int* pdst = (int*)partial + (size_t)(a * NCHUNK + c) * words;
  for (int i = tid; i < words; i += 1024) pdst[i] = histw[i];
}

// ---------- FUSED build tail: dinv/indeg reduce + scan -> base emit -> bin2 ----------
// 128 blocks x 1024 thr, 50KB LDS union. Grid barriers between phases.
__global__ __launch_bounds__(1024) void k_build(
    const int* __restrict__ ei,
    const unsigned short* __restrict__ partial,
    float* __restrict__ dinv, int* __restrict__ indeg,
    int* __restrict__ ptr, int* __restrict__ base,
    int* __restrict__ csr_row, int* __restrict__ bsum,
    int* __restrict__ bars,
    int N, int E, int range_b) {
  __shared__ int smem[HIST_B2];   // union: 1024-scan | 128-scan | bin2 cnt (50KB)
  const int tid = threadIdx.x;
  const int b = blockIdx.x;
  const int nbB = NB_BUILD;
  const int sw = (N + 1) & ~1;
  const int npb = (N + nbB - 1) / nbB;      // 391 nodes per block
  const int g = b * npb + tid;

  // ---- phase 1: reduce u16 partials -> deg/ind; in-block exclusive scan ----
  int ind = 0;
  if (tid < npb && g < N) {
    int deg = 0;
#pragma unroll
    for (int c = 0; c < NCHUNK; ++c) {
      deg += partial[(size_t)c * sw + g];
      ind += partial[(size_t)(NCHUNK + c) * sw + g];
    }
    dinv[g] = (deg > 0) ? (1.0f / sqrtf((float)deg)) : 0.0f;
    indeg[g] = ind;
  }
  smem[tid] = ind;
  __syncthreads();
  for (int off = 1; off < 1024; off <<= 1) {
    int tv = (tid >= off) ? smem[tid - off] : 0;
    __syncthreads();
    smem[tid] += tv;
    __syncthreads();
  }
  const int ex = smem[tid] - ind;           // exclusive within block (register)
  if (tid == 0) bsum[b] = smem[1023];

  gsync(&bars[0], &bars[1], nbB);

  // ---- phase 2: redundant 128-wide bsum scan; finalize ptr; emit bases ----
  smem[tid] = (tid < nbB) ? bsum[tid] : 0;
  __syncthreads();
  for (int off = 1; off < 1024; off <<= 1) {
    int tv = (tid >= off) ? smem[tid - off] : 0;
    __syncthreads();
    smem[tid] += tv;
    __syncthreads();
  }
  const int pb = (b == 0) ? 0 : smem[b - 1];   // LDS broadcast
  if (tid < npb && g < N) {
    int run = ex + pb;
    ptr[g] = run;                              // global exclusive scan
#pragma unroll
    for (int c = 0; c < NCHUNK; ++c) {
      base[(size_t)c * N + g] = run;
      run += partial[(size_t)(NCHUNK + c) * sw + g];
    }
  }

  gsync(&bars[0], &bars[1], nbB);

  // ---- phase 3: counting-sort binning (LDS atomics on cnt; base from L2) ----
  int c = b % NCHUNK;
  int r = b / NCHUNK;
  const int* row = ei;
  const int* col = ei + E;
  int lo = r * range_b;
  int hi = min(N, lo + range_b);
  int len = hi - lo;
  for (int i = tid; i < len; i += 1024) smem[i] = 0;
  __syncthreads();
  int e0 = (int)((long long)E * c / NCHUNK);
  int e1 = (int)((long long)E * (c + 1) / NCHUNK);
  const int* bslice = base + (size_t)c * N;
  for (int e = e0 + tid; e < e1; e += 1024) {
    int cl = col[e];
    if (cl >= lo && cl < hi) {
      int rw = row[e];                         // load only when in range
      int off = atomicAdd(&smem[cl - lo], 1);  // LDS atomic
      csr_row[bslice[cl] + off] = rw;          // base in L2; plain store
    }
  }
}

// ---------- FUSED layer-1 gather + layer-2 dual GEMM ----------
// Block = 1024 thr, 64 nodes. Phase 1: each 16-lane group gathers one node's
// aggregate (lane-local, no shuffles) into LDS hrows (stride 68 = bank skew).
// Phase 2: waves 0..3 MFMA layer-2 from LDS: t2 = relu(h2)@Wn2 * dinv (prescaled),
// agg = relu(h2)@Wi2 + b2 (in place).
__global__ __launch_bounds__(1024) void k_gather_gemm2(
    const int* __restrict__ csr_row, const int* __restrict__ ptr,
    const int* __restrict__ indeg, const float* __restrict__ dinv,
    const __hip_bfloat16* __restrict__ t1, float* __restrict__ agg,
    const float* __restrict__ Wn, const float* __restrict__ Wi,
    const float* __restrict__ bias,
    __hip_bfloat16* __restrict__ t2, int N) {
  __shared__ short Wn_f[4096];       // 8 KB
  __shared__ short Wi_f[4096];       // 8 KB
  __shared__ float b_s[64];
  __shared__ float hrows[64 * 68];   // 64 nodes x 64 dims f32, +4 pad (17 KB)

  const int tid = threadIdx.x;
  stage_W_frag(Wn, Wi, Wn_f, Wi_f, tid, 1024);
  if (tid < 64) b_s[tid] = bias[tid];

  const int w = tid >> 6;
  const int lane = tid & 63;
  const int q = lane >> 4;        // node-group within wave
  const int fl = lane & 15;       // 4 dims per lane
  const int nn = w * 4 + q;       // local node 0..63
  const int base = (int)blockIdx.x * 64;
  const int n = base + nn;

  // ---- phase 1: gather h2pre rows into LDS ----
  if (n < N) {
    int i0 = ptr[n];
    int end = i0 + indeg[n];
    float dn = dinv[n];
    float4 acc = make_float4(0.f, 0.f, 0.f, 0.f);
    int i = i0;
    for (; i + 1 < end; i += 2) {
      int ra = csr_row[i];
      int rb = csr_row[i + 1];
      float na = dinv[ra];
      float nb = dinv[rb];
      ushort4 ua = *(const ushort4*)&t1[(size_t)ra * 64 + 4 * fl];
      ushort4 ub = *(const ushort4*)&t1[(size_t)rb * 64 + 4 * fl];
      float4 va, vb;
      ((unsigned*)&va)[0] = (unsigned)ua.x << 16; ((unsigned*)&va)[1] = (unsigned)ua.y << 16;
      ((unsigned*)&va)[2] = (unsigned)ua.z << 16; ((unsigned*)&va)[3] = (unsigned)ua.w << 16;
      ((unsigned*)&vb)[0] = (unsigned)ub.x << 16; ((unsigned*)&vb)[1] = (unsigned)ub.y << 16;
      ((unsigned*)&vb)[2] = (unsigned)ub.z << 16; ((unsigned*)&vb)[3] = (unsigned)ub.w << 16;
      acc.x = fmaf(va.x, na, acc.x); acc.y = fmaf(va.y, na, acc.y);
      acc.z = fmaf(va.z, na, acc.z); acc.w = fmaf(va.w, na, acc.w);
      acc.x = fmaf(vb.x, nb, acc.x); acc.y = fmaf(vb.y, nb, acc.y);
      acc.z = fmaf(vb.z, nb, acc.z); acc.w = fmaf(vb.w, nb, acc.w);
    }
    if (i < end) {
      int ra = csr_row[i];
      float na = dinv[ra];
      ushort4 ua = *(const ushort4*)&t1[(size_t)ra * 64 + 4 * fl];
      float4 va;
      ((unsigned*)&va)[0] = (unsigned)ua.x << 16; ((unsigned*)&va)[1] = (unsigned)ua.y << 16;
      ((unsigned*)&va)[2] = (unsigned)ua.z << 16; ((unsigned*)&va)[3] = (unsigned)ua.w << 16;
      acc.x = fmaf(va.x, na, acc.x); acc.y = fmaf(va.y, na, acc.y);
      acc.z = fmaf(va.z, na, acc.z); acc.w = fmaf(va.w, na, acc.w);
    }
    float4 aggv = *(const float4*)&agg[(size_t)n * 64 + 4 * fl];
    f32x4 hv = {aggv.x + dn * acc.x, aggv.y + dn * acc.y,
                aggv.z + dn * acc.z, aggv.w + dn * acc.w};
    *(f32x4*)&hrows[nn * 68 + 4 * fl] = hv;
  } else {
    f32x4 z = {0.f, 0.f, 0.f, 0.f};
    *(f32x4*)&hrows[nn * 68 + 4 * fl] = z;
  }
  __syncthreads();

  // ---- phase 2: layer-2 dual GEMM from LDS (waves 0..3, 16 rows each) ----
  if (w >= 4) return;
  const int m = fl;
  const int quad = q;

  bfrag Bn[4][2], Bi[4][2];
#pragma unroll
  for (int ct = 0; ct < 4; ++ct)
#pragma unroll
    for (int kb = 0; kb < 2; ++kb) {
      Bn[ct][kb] = *(const bfrag*)&Wn_f[((ct * 2 + kb) * 64 + lane) * 8];
      Bi[ct][kb] = *(const bfrag*)&Wi_f[((ct * 2 + kb) * 64 + lane) * 8];
    }

  bfrag A[2];
#pragma unroll
  for (int kb = 0; kb < 2; ++kb) {
    const float* src = &hrows[(w * 16 + m) * 68 + kb * 32 + quad * 8];
    float4 f0 = *(const float4*)src;
    float4 f1 = *(const float4*)(src + 4);
    float tmp[8] = {f0.x, f0.y, f0.z, f0.w, f1.x, f1.y, f1.z, f1.w};
    bfrag av;
#pragma unroll
    for (int j = 0; j < 8; ++j) {
      float v = fmaxf(tmp[j], 0.f);          // relu(h2pre)
      __hip_bfloat16 hb = __float2bfloat16(v);
      av[j] = *(short*)&hb;
    }
    A[kb] = av;
  }

  f32x4 accT[4], accA[4];
#pragma unroll
  for (int ct = 0; ct < 4; ++ct) {
    f32x4 z = {0.f, 0.f, 0.f, 0.f};
    accT[ct] = z;
    accA[ct] = z;
  }
#pragma unroll
  for (int ct = 0; ct < 4; ++ct) {
    accT[ct] = __builtin_amdgcn_mfma_f32_16x16x32_bf16(A[0], Bn[ct][0], accT[ct], 0, 0, 0);
    accT[ct] = __builtin_amdgcn_mfma_f32_16x16x32_bf16(A[1], Bn[ct][1], accT[ct], 0, 0, 0);
    accA[ct] = __builtin_amdgcn_mfma_f32_16x16x32_bf16(A[0], Bi[ct][0], accA[ct], 0, 0, 0);
    accA[ct] = __builtin_amdgcn_mfma_f32_16x16x32_bf16(A[1], Bi[ct][1], accA[ct], 0, 0, 0);
  }

#pragma unroll
  for (int reg = 0; reg < 4; ++reg) {
    int r = base + w * 16 + quad * 4 + reg;
    if (r < N) {
      float dv = dinv[r];
#pragma unroll
      for (int ct = 0; ct < 4; ++ct) {
        int col = ct * 16 + m;
        t2[(size_t)r * 64 + col] = __float2bfloat16(accT[ct][reg] * dv);
        agg[(size_t)r * 64 + col] = accA[ct][reg] + b_s[col];
      }
    }
  }
}

// ---------- FUSED layer-2 gather + output GEMM (t2 prescaled: pure-add) ----------
__global__ __launch_bounds__(256) void k_gather_out(
    const int* __restrict__ csr_row, const int* __restrict__ ptr,
    const int* __restrict__ indeg, const float* __restrict__ dinv,
    const __hip_bfloat16* __restrict__ t, const float* __restrict__ agg,
    const float* __restrict__ Wo,   // [64,32]
    const float* __restrict__ bo,   // [32]
    float* __restrict__ out, int N) {
  __shared__ float Wo_s[64 * 32];
  __shared__ float bo_s[32];
  __shared__ float rowbuf[4][64];

  const int tid = threadIdx.x;
  for (int i = tid; i < 2048; i += 256) Wo_s[i] = Wo[i];
  if (tid < 32) bo_s[tid] = bo[tid];
  __syncthreads();   // barrier BEFORE any divergent exit

  int w = tid >> 6;
  int n = blockIdx.x * 4 + w;
  if (n >= N) return;
  int lane = tid & 63;
  int q = lane >> 4;
  int fl = lane & 15;
  int i0 = ptr[n];
  int end = i0 + indeg[n];
  float dn = dinv[n];

  float4 aggv = make_float4(0.f, 0.f, 0.f, 0.f);
  if (q == 0) aggv = *(const float4*)&agg[(size_t)n * 64 + 4 * fl];

  float4 acc = make_float4(0.f, 0.f, 0.f, 0.f);
  int i = i0 + q;
  for (; i + 4 < end; i += 8) {
    int ra = csr_row[i];
    int rb = csr_row[i + 4];
    ushort4 ua = *(const ushort4*)&t[(size_t)ra * 64 + 4 * fl];
    ushort4 ub = *(const ushort4*)&t[(size_t)rb * 64 + 4 * fl];
    float4 va, vb;
    ((unsigned*)&va)[0] = (unsigned)ua.x << 16; ((unsigned*)&va)[1] = (unsigned)ua.y << 16;
    ((unsigned*)&va)[2] = (unsigned)ua.z << 16; ((unsigned*)&va)[3] = (unsigned)ua.w << 16;
    ((unsigned*)&vb)[0] = (unsigned)ub.x << 16; ((unsigned*)&vb)[1] = (unsigned)ub.y << 16;
    ((unsigned*)&vb)[2] = (unsigned)ub.z << 16; ((unsigned*)&vb)[3] = (unsigned)ub.w << 16;
    acc.x += va.x + vb.x; acc.y += va.y + vb.y;
    acc.z += va.z + vb.z; acc.w += va.w + vb.w;
  }
  for (; i < end; i += 4) {
    int ra = csr_row[i];
    ushort4 ua = *(const ushort4*)&t[(size_t)ra * 64 + 4 * fl];
    float4 va;
    ((unsigned*)&va)[0] = (unsigned)ua.x << 16; ((unsigned*)&va)[1] = (unsigned)ua.y << 16;
    ((unsigned*)&va)[2] = (unsigned)ua.z << 16; ((unsigned*)&va)[3] = (unsigned)ua.w << 16;
    acc.x += va.x; acc.y += va.y; acc.z += va.z; acc.w += va.w;
  }
  acc.x += __shfl_xor(acc.x, 16); acc.y += __shfl_xor(acc.y, 16);
  acc.z += __shfl_xor(acc.z, 16); acc.w += __shfl_xor(acc.w, 16);
  acc.x += __shfl_xor(acc.x, 32); acc.y += __shfl_xor(acc.y, 32);
  acc.z += __shfl_xor(acc.z, 32); acc.w += __shfl_xor(acc.w, 32);
  if (q == 0) {
    rowbuf[w][4 * fl + 0] = fmaxf(aggv.x + dn * acc.x, 0.f);
    rowbuf[w][4 * fl + 1] = fmaxf(aggv.y + dn * acc.y, 0.f);
    rowbuf[w][4 * fl + 2] = fmaxf(aggv.z + dn * acc.z, 0.f);
    rowbuf[w][4 * fl + 3] = fmaxf(aggv.w + dn * acc.w, 0.f);
  }
  // same-wave LDS RAW: compiler inserts lgkmcnt wait; no barrier needed.
  int half = lane >> 5;
  int j = lane & 31;
  float ov = 0.f;
#pragma unroll 8
  for (int k = 32 * half; k < 32 * half + 32; ++k)
    ov = fmaf(rowbuf[w][k], Wo_s[k * 32 + j], ov);
  ov += __shfl_xor(ov, 32);
  if (half == 0) out[(size_t)n * 32 + j] = ov + bo_s[j];
}

extern "C" void kernel_launch(void* const* d_in, const int* in_sizes, int n_in,
                              void* d_out, int out_size, void* d_ws, size_t ws_size,
                              hipStream_t stream) {
  const float* x = (const float*)d_in[0];
  const int* ei = (const int*)d_in[1];
  const float* W_in1 = (const float*)d_in[2];
  const float* W_neigh1 = (const float*)d_in[3];
  const float* bias1 = (const float*)d_in[4];
  const float* W_in2 = (const float*)d_in[5];
  const float* W_neigh2 = (const float*)d_in[6];
  const float* bias2 = (const float*)d_in[7];
  const float* W_out = (const float*)d_in[8];
  const float* b_out = (const float*)d_in[9];
  float* out = (float*)d_out;

  const int N = in_sizes[0] / 64;
  const int E = in_sizes[1] / 2;

  char* ws = (char*)d_ws;
  size_t off = 0;
  auto alloc = [&](size_t bytes) -> void* {
    void* p = ws + off;
    off += (bytes + 255) & ~(size_t)255;
    return p;
  };
  const int sw = (N + 1) & ~1;
  float* dinv = (float*)alloc((size_t)N * 4);
  int* indeg = (int*)alloc((size_t)N * 4);
  int* ptr = (int*)alloc((size_t)N * 4);
  int* bsum = (int*)alloc(1024);
  int* bars = (int*)alloc(256);
  int* csr_row = (int*)alloc((size_t)E * 4);
  unsigned short* partial = (unsigned short*)alloc((size_t)2 * NCHUNK * sw * 2);
  int* base = (int*)alloc((size_t)NCHUNK * N * 4);
  __hip_bfloat16* t = (__hip_bfloat16*)alloc((size_t)N * 64 * 2);
  __hip_bfloat16* t2 = (__hip_bfloat16*)alloc((size_t)N * 64 * 2);
  float* agg = (float*)alloc((size_t)N * 64 * 4);
  (void)ws_size;

  int range_b = (N + NRANGE_B - 1) / NRANGE_B;  // 12500 <= HIST_B2
  int gNode = (N + 3) / 4;
  int gFused = (N + 63) / 64;
  int gemmBlocks = (N + 255) / 256;             // 256 rows per 1024-thread block

  // dispatch 1: layer-1 GEMM (independent of build) fused with full-range hist
  k_hist_gemm1<<<gemmBlocks + 2 * NCHUNK, 1024, 0, stream>>>(
      ei, partial, x, W_neigh1, W_in1, bias1, t, agg, bars, N, E, gemmBlocks);

  // dispatch 2: fused build tail (dinv/indeg + scan -> base -> bin2)
  k_build<<<NB_BUILD, 1024, 0, stream>>>(ei, partial, dinv, indeg, ptr, base,
                                         csr_row, bsum, bars, N, E, range_b);

  // dispatch 3: fused layer-1 gather + layer-2 dual GEMM
  k_gather_gemm2<<<gFused, 1024, 0, stream>>>(csr_row, ptr, indeg, dinv, t, agg,
                                              W_neigh2, W_in2, bias2, t2, N);

  // dispatch 4: fused layer-2 gather + output GEMM
  k_gather_out<<<gNode, 256, 0, stream>>>(csr_row, ptr, indeg, dinv, t2, agg,
                                          W_out, b_out, out, N);
}

// Round 6
// 189.063 us; speedup vs baseline: 1.1175x; 1.1175x over previous
//
#include <hip/hip_runtime.h>
#include <hip/hip_bf16.h>

// Pipeline (no global atomics for data — write through to HBM per-op; r3/4).
// Gathers are at the per-XCD compulsory-miss x per-request floor (r17 fit:
// ~22us requests + ~22us bytes per 800K x 128B pass); parked. r18: layer-2
// GEMM fused into layer-1 gather. r19/r20: u16 hist/partial diet (190.2us).
// r21: k_build grid-barrier fusion FAILED (+21us) but exposed bin2 = ~40us
// (not ~13): 128 blocks = half chip idle + 800K random L2 base reads.
// Round 22 (this): revert to r20's 6-dispatch structure; rebuild bin2 —
// (a) LDS cnt INITIALIZED TO BASE VALUES: atomicAdd returns the csr position
//     directly, deleting the per-edge random L2 base read;
// (b) NRANGE_B 4->8: 256 blocks (full chip), 25KB LDS/block.
// Gathers / GEMM fusions untouched.

#define NCHUNK 32     // edge chunks
#define NRANGE_B 8    // bin2 node ranges (range = 6250) -> 256 blocks
#define HIST_B2 6272
#define SMEM1 100352  // dispatch-1 union: 25088 words (full-range u16 hist) | W frags

typedef __attribute__((ext_vector_type(8))) short bfrag;   // 8 bf16 = 4 VGPRs
typedef __attribute__((ext_vector_type(4))) float f32x4;

// ---------- MFMA 16-row wave tile: t = h@Wn (opt *dinv), agg = h@Wi + bias ----------
// W LDS layout is FRAGMENT ORDER: frag (ct,kb) at shorts [((ct*2+kb)*64+lane)*8].
template <bool RELU, bool PRESCALE>
__device__ __forceinline__ void gemm_tile16(
    const float* h, const float* __restrict__ dinv,
    const short* Wn_f, const short* Wi_f, const float* b_s,
    __hip_bfloat16* __restrict__ t, float* agg, int r0, int lane, int N) {
  const int m = lane & 15;
  const int quad = lane >> 4;

  bfrag Bn[4][2], Bi[4][2];
#pragma unroll
  for (int ct = 0; ct < 4; ++ct)
#pragma unroll
    for (int kb = 0; kb < 2; ++kb) {
      Bn[ct][kb] = *(const bfrag*)&Wn_f[((ct * 2 + kb) * 64 + lane) * 8];
      Bi[ct][kb] = *(const bfrag*)&Wi_f[((ct * 2 + kb) * 64 + lane) * 8];
    }

  const int arow = r0 + m;
  bfrag A[2];
#pragma unroll
  for (int kb = 0; kb < 2; ++kb) {
    bfrag av = {};
    if (arow < N) {
      const float* src = &h[(size_t)arow * 64 + kb * 32 + quad * 8];
      float4 f0 = *(const float4*)src;
      float4 f1 = *(const float4*)(src + 4);
      float tmp[8] = {f0.x, f0.y, f0.z, f0.w, f1.x, f1.y, f1.z, f1.w};
#pragma unroll
      for (int j = 0; j < 8; ++j) {
        float v = RELU ? fmaxf(tmp[j], 0.f) : tmp[j];
        __hip_bfloat16 hb = __float2bfloat16(v);
        av[j] = *(short*)&hb;
      }
    }
    A[kb] = av;
  }

  f32x4 accT[4], accA[4];
#pragma unroll
  for (int ct = 0; ct < 4; ++ct) {
    f32x4 z = {0.f, 0.f, 0.f, 0.f};
    accT[ct] = z;
    accA[ct] = z;
  }
#pragma unroll
  for (int ct = 0; ct < 4; ++ct) {
    accT[ct] = __builtin_amdgcn_mfma_f32_16x16x32_bf16(A[0], Bn[ct][0], accT[ct], 0, 0, 0);
    accT[ct] = __builtin_amdgcn_mfma_f32_16x16x32_bf16(A[1], Bn[ct][1], accT[ct], 0, 0, 0);
    accA[ct] = __builtin_amdgcn_mfma_f32_16x16x32_bf16(A[0], Bi[ct][0], accA[ct], 0, 0, 0);
    accA[ct] = __builtin_amdgcn_mfma_f32_16x16x32_bf16(A[1], Bi[ct][1], accA[ct], 0, 0, 0);
  }

#pragma unroll
  for (int reg = 0; reg < 4; ++reg) {
    int r = r0 + quad * 4 + reg;
    if (r < N) {
      float dv = PRESCALE ? dinv[r] : 1.0f;
#pragma unroll
      for (int ct = 0; ct < 4; ++ct) {
        int col = ct * 16 + m;
        float tv = PRESCALE ? accT[ct][reg] * dv : accT[ct][reg];
        t[(size_t)r * 64 + col] = __float2bfloat16(tv);
        agg[(size_t)r * 64 + col] = accA[ct][reg] + b_s[col];
      }
    }
  }
}

// W staging in fragment order (256 or 1024 threads)
__device__ __forceinline__ void stage_W_frag(const float* __restrict__ Wn,
                                             const float* __restrict__ Wi,
                                             short* Wn_f, short* Wi_f,
                                             int tid, int nthr) {
  for (int i = tid; i < 4096; i += nthr) {
    int k = i >> 6, n = i & 63;
    int dst = (((n >> 4) * 2 + (k >> 5)) * 64 + ((k >> 3) & 3) * 16 + (n & 15)) * 8 + (k & 7);
    __hip_bfloat16 a = __float2bfloat16(Wn[i]);
    __hip_bfloat16 b = __float2bfloat16(Wi[i]);
    Wn_f[dst] = *(short*)&a;
    Wi_f[dst] = *(short*)&b;
  }
}

// ---------- FUSED dispatch 1: layer-1 GEMM blocks + full-range u16 histogram ----------
__global__ __launch_bounds__(1024) void k_hist_gemm1(
    const int* __restrict__ ei, unsigned short* __restrict__ partial,
    const float* __restrict__ x,
    const float* __restrict__ Wn, const float* __restrict__ Wi,
    const float* __restrict__ bias,
    __hip_bfloat16* __restrict__ t, float* __restrict__ agg,
    int N, int E, int gemmBlocks) {
  __shared__ __align__(16) char smem[SMEM1];   // union: u16 hist | W frags
  const int tid = threadIdx.x;

  if ((int)blockIdx.x < gemmBlocks) {
    short* Wn_f = (short*)smem;                     // 8192 B
    short* Wi_f = (short*)(smem + 8192);            // 8192 B
    float* b_s = (float*)(smem + 16384);            // 256 B
    stage_W_frag(Wn, Wi, Wn_f, Wi_f, tid, 1024);
    if (tid < 64) b_s[tid] = bias[tid];
    __syncthreads();
    int w = tid >> 6;
    int lane = tid & 63;
    int r0 = blockIdx.x * 256 + w * 16;
    gemm_tile16<false, false>(x, nullptr, Wn_f, Wi_f, b_s, t, agg, r0, lane, N);
    return;
  }

  int* histw = (int*)smem;
  int bid = blockIdx.x - gemmBlocks;
  int c = bid % NCHUNK;
  int a = bid / NCHUNK;
  const int* ids = ei + (size_t)a * E;
  const int sw = (N + 1) & ~1;      // even u16 stride
  const int words = sw >> 1;
  for (int i = tid; i < words; i += 1024) histw[i] = 0;
  __syncthreads();
  int e0 = (int)((long long)E * c / NCHUNK);
  int e1 = (int)((long long)E * (c + 1) / NCHUNK);
  for (int e = e0 + tid; e < e1; e += 1024) {
    int s = ids[e];
    atomicAdd(&histw[s >> 1], 1 << ((s & 1) * 16));  // LDS atomic, packed u16
  }
  __syncthreads();
  int* pdst = (int*)partial + (size_t)(a * NCHUNK + c) * words;
  for (int i = tid; i < words; i += 1024) pdst[i] = histw[i];
}

// ---------- fused: reduce u16 partials -> dinv/indeg, then in-block exscan ----------
__global__ __launch_bounds__(256) void k_dinv_scan(const unsigned short* __restrict__ partial,
                                                   float* __restrict__ dinv,
                                                   int* __restrict__ indeg,
                                                   int* __restrict__ ptr,
                                                   int* __restrict__ bsum, int N) {
  __shared__ int s[256];
  const int sw = (N + 1) & ~1;
  int g = blockIdx.x * 256 + threadIdx.x;
  int deg = 0, ind = 0;
  if (g < N) {
#pragma unroll
    for (int c = 0; c < NCHUNK; ++c) {
      deg += partial[(size_t)c * sw + g];
      ind += partial[(size_t)(NCHUNK + c) * sw + g];
    }
    dinv[g] = (deg > 0) ? (1.0f / sqrtf((float)deg)) : 0.0f;
    indeg[g] = ind;
  }
  s[threadIdx.x] = ind;
  __syncthreads();
  for (int off = 1; off < 256; off <<= 1) {
    int tv = (threadIdx.x >= off) ? s[threadIdx.x - off] : 0;
    __syncthreads();
    s[threadIdx.x] += tv;
    __syncthreads();
  }
  if (g < N) ptr[g] = s[threadIdx.x] - ind;  // exclusive within block
  if (threadIdx.x == 255) bsum[blockIdx.x] = s[255];
}

// ---------- fused: parallel scan bsum (LDS) + finalize ptr + emit bases ----------
__global__ __launch_bounds__(256) void k_base(const unsigned short* __restrict__ partial,
                                              const int* __restrict__ bsum,
                                              int* __restrict__ ptr,
                                              int* __restrict__ base, int N, int nb) {
  __shared__ int sb[256];
  const int sw = (N + 1) & ~1;
  int v = (threadIdx.x < nb) ? bsum[threadIdx.x] : 0;
  sb[threadIdx.x] = v;
  __syncthreads();
  for (int off = 1; off < 256; off <<= 1) {
    int tv = (threadIdx.x >= off) ? sb[threadIdx.x - off] : 0;
    __syncthreads();
    sb[threadIdx.x] += tv;
    __syncthreads();
  }
  __shared__ int pbs[256];
  pbs[threadIdx.x] = sb[threadIdx.x] - v;   // exclusive
  __syncthreads();
  int n = blockIdx.x * 256 + threadIdx.x;
  if (n >= N) return;
  int run = ptr[n] + pbs[n >> 8];           // dinv_scan blocks are 256 wide
  ptr[n] = run;                             // final global exclusive scan
#pragma unroll
  for (int c = 0; c < NCHUNK; ++c) {
    base[(size_t)c * N + n] = run;
    run += partial[(size_t)(NCHUNK + c) * sw + n];
  }
}

// ---------- counting-sort binning: LDS cnt PRE-LOADED WITH BASE ----------
// atomicAdd on the base-initialized counter returns the csr position directly
// (no per-edge random L2 base read). 256 blocks = (8 ranges x 32 chunks).
__global__ __launch_bounds__(1024) void k_bin2(const int* __restrict__ ei,
                                               const int* __restrict__ base,
                                               int* __restrict__ csr_row,
                                               int N, int E, int range) {
  __shared__ int cnt[HIST_B2];   // 25 KB: running csr positions
  int c = blockIdx.x % NCHUNK;
  int r = blockIdx.x / NCHUNK;
  const int* row = ei;
  const int* col = ei + E;
  int lo = r * range;
  int hi = min(N, lo + range);
  int len = hi - lo;
  const int* bslice = base + (size_t)c * N + lo;
  for (int i = threadIdx.x; i < len; i += 1024) cnt[i] = bslice[i];  // coalesced
  __syncthreads();
  int e0 = (int)((long long)E * c / NCHUNK);
  int e1 = (int)((long long)E * (c + 1) / NCHUNK);
  for (int e = e0 + threadIdx.x; e < e1; e += 1024) {
    int cl = col[e];
    if (cl >= lo && cl < hi) {
      int rw = row[e];                         // load only when in range
      int pos = atomicAdd(&cnt[cl - lo], 1);   // LDS atomic -> csr position
      csr_row[pos] = rw;
    }
  }
}

// ---------- FUSED layer-1 gather + layer-2 dual GEMM ----------
// Block = 1024 thr, 64 nodes. Phase 1: each 16-lane group gathers one node's
// aggregate (lane-local, no shuffles) into LDS hrows (stride 68 = bank skew).
// Phase 2: waves 0..3 MFMA layer-2 from LDS: t2 = relu(h2)@Wn2 * dinv (prescaled),
// agg = relu(h2)@Wi2 + b2 (in place).
__global__ __launch_bounds__(1024) void k_gather_gemm2(
    const int* __restrict__ csr_row, const int* __restrict__ ptr,
    const int* __restrict__ indeg, const float* __restrict__ dinv,
    const __hip_bfloat16* __restrict__ t1, float* __restrict__ agg,
    const float* __restrict__ Wn, const float* __restrict__ Wi,
    const float* __restrict__ bias,
    __hip_bfloat16* __restrict__ t2, int N) {
  __shared__ short Wn_f[4096];       // 8 KB
  __shared__ short Wi_f[4096];       // 8 KB
  __shared__ float b_s[64];
  __shared__ float hrows[64 * 68];   // 64 nodes x 64 dims f32, +4 pad (17 KB)

  const int tid = threadIdx.x;
  stage_W_frag(Wn, Wi, Wn_f, Wi_f, tid, 1024);
  if (tid < 64) b_s[tid] = bias[tid];

  const int w = tid >> 6;
  const int lane = tid & 63;
  const int q = lane >> 4;        // node-group within wave
  const int fl = lane & 15;       // 4 dims per lane
  const int nn = w * 4 + q;       // local node 0..63
  const int base = (int)blockIdx.x * 64;
  const int n = base + nn;

  // ---- phase 1: gather h2pre rows into LDS ----
  if (n < N) {
    int i0 = ptr[n];
    int end = i0 + indeg[n];
    float dn = dinv[n];
    float4 acc = make_float4(0.f, 0.f, 0.f, 0.f);
    int i = i0;
    for (; i + 1 < end; i += 2) {
      int ra = csr_row[i];
      int rb = csr_row[i + 1];
      float na = dinv[ra];
      float nb = dinv[rb];
      ushort4 ua = *(const ushort4*)&t1[(size_t)ra * 64 + 4 * fl];
      ushort4 ub = *(const ushort4*)&t1[(size_t)rb * 64 + 4 * fl];
      float4 va, vb;
      ((unsigned*)&va)[0] = (unsigned)ua.x << 16; ((unsigned*)&va)[1] = (unsigned)ua.y << 16;
      ((unsigned*)&va)[2] = (unsigned)ua.z << 16; ((unsigned*)&va)[3] = (unsigned)ua.w << 16;
      ((unsigned*)&vb)[0] = (unsigned)ub.x << 16; ((unsigned*)&vb)[1] = (unsigned)ub.y << 16;
      ((unsigned*)&vb)[2] = (unsigned)ub.z << 16; ((unsigned*)&vb)[3] = (unsigned)ub.w << 16;
      acc.x = fmaf(va.x, na, acc.x); acc.y = fmaf(va.y, na, acc.y);
      acc.z = fmaf(va.z, na, acc.z); acc.w = fmaf(va.w, na, acc.w);
      acc.x = fmaf(vb.x, nb, acc.x); acc.y = fmaf(vb.y, nb, acc.y);
      acc.z = fmaf(vb.z, nb, acc.z); acc.w = fmaf(vb.w, nb, acc.w);
    }
    if (i < end) {
      int ra = csr_row[i];
      float na = dinv[ra];
      ushort4 ua = *(const ushort4*)&t1[(size_t)ra * 64 + 4 * fl];
      float4 va;
      ((unsigned*)&va)[0] = (unsigned)ua.x << 16; ((unsigned*)&va)[1] = (unsigned)ua.y << 16;
      ((unsigned*)&va)[2] = (unsigned)ua.z << 16; ((unsigned*)&va)[3] = (unsigned)ua.w << 16;
      acc.x = fmaf(va.x, na, acc.x); acc.y = fmaf(va.y, na, acc.y);
      acc.z = fmaf(va.z, na, acc.z); acc.w = fmaf(va.w, na, acc.w);
    }
    float4 aggv = *(const float4*)&agg[(size_t)n * 64 + 4 * fl];
    f32x4 hv = {aggv.x + dn * acc.x, aggv.y + dn * acc.y,
                aggv.z + dn * acc.z, aggv.w + dn * acc.w};
    *(f32x4*)&hrows[nn * 68 + 4 * fl] = hv;
  } else {
    f32x4 z = {0.f, 0.f, 0.f, 0.f};
    *(f32x4*)&hrows[nn * 68 + 4 * fl] = z;
  }
  __syncthreads();

  // ---- phase 2: layer-2 dual GEMM from LDS (waves 0..3, 16 rows each) ----
  if (w >= 4) return;
  const int m = fl;
  const int quad = q;

  bfrag Bn[4][2], Bi[4][2];
#pragma unroll
  for (int ct = 0; ct < 4; ++ct)
#pragma unroll
    for (int kb = 0; kb < 2; ++kb) {
      Bn[ct][kb] = *(const bfrag*)&Wn_f[((ct * 2 + kb) * 64 + lane) * 8];
      Bi[ct][kb] = *(const bfrag*)&Wi_f[((ct * 2 + kb) * 64 + lane) * 8];
    }

  bfrag A[2];
#pragma unroll
  for (int kb = 0; kb < 2; ++kb) {
    const float* src = &hrows[(w * 16 + m) * 68 + kb * 32 + quad * 8];
    float4 f0 = *(const float4*)src;
    float4 f1 = *(const float4*)(src + 4);
    float tmp[8] = {f0.x, f0.y, f0.z, f0.w, f1.x, f1.y, f1.z, f1.w};
    bfrag av;
#pragma unroll
    for (int j = 0; j < 8; ++j) {
      float v = fmaxf(tmp[j], 0.f);          // relu(h2pre)
      __hip_bfloat16 hb = __float2bfloat16(v);
      av[j] = *(short*)&hb;
    }
    A[kb] = av;
  }

  f32x4 accT[4], accA[4];
#pragma unroll
  for (int ct = 0; ct < 4; ++ct) {
    f32x4 z = {0.f, 0.f, 0.f, 0.f};
    accT[ct] = z;
    accA[ct] = z;
  }
#pragma unroll
  for (int ct = 0; ct < 4; ++ct) {
    accT[ct] = __builtin_amdgcn_mfma_f32_16x16x32_bf16(A[0], Bn[ct][0], accT[ct], 0, 0, 0);
    accT[ct] = __builtin_amdgcn_mfma_f32_16x16x32_bf16(A[1], Bn[ct][1], accT[ct], 0, 0, 0);
    accA[ct] = __builtin_amdgcn_mfma_f32_16x16x32_bf16(A[0], Bi[ct][0], accA[ct], 0, 0, 0);
    accA[ct] = __builtin_amdgcn_mfma_f32_16x16x32_bf16(A[1], Bi[ct][1], accA[ct], 0, 0, 0);
  }

#pragma unroll
  for (int reg = 0; reg < 4; ++reg) {
    int r = base + w * 16 + quad * 4 + reg;
    if (r < N) {
      float dv = dinv[r];
#pragma unroll
      for (int ct = 0; ct < 4; ++ct) {
        int col = ct * 16 + m;
        t2[(size_t)r * 64 + col] = __float2bfloat16(accT[ct][reg] * dv);
        agg[(size_t)r * 64 + col] = accA[ct][reg] + b_s[col];
      }
    }
  }
}

// ---------- FUSED layer-2 gather + output GEMM (t2 prescaled: pure-add) ----------
__global__ __launch_bounds__(256) void k_gather_out(
    const int* __restrict__ csr_row, const int* __restrict__ ptr,
    const int* __restrict__ indeg, const float* __restrict__ dinv,
    const __hip_bfloat16* __restrict__ t, const float* __restrict__ agg,
    const float* __restrict__ Wo,   // [64,32]
    const float* __restrict__ bo,   // [32]
    float* __restrict__ out, int N) {
  __shared__ float Wo_s[64 * 32];
  __shared__ float bo_s[32];
  __shared__ float rowbuf[4][64];

  const int tid = threadIdx.x;
  for (int i = tid; i < 2048; i += 256) Wo_s[i] = Wo[i];
  if (tid < 32) bo_s[tid] = bo[tid];
  __syncthreads();   // barrier BEFORE any divergent exit

  int w = tid >> 6;
  int n = blockIdx.x * 4 + w;
  if (n >= N) return;
  int lane = tid & 63;
  int q = lane >> 4;
  int fl = lane & 15;
  int i0 = ptr[n];
  int end = i0 + indeg[n];
  float dn = dinv[n];

  float4 aggv = make_float4(0.f, 0.f, 0.f, 0.f);
  if (q == 0) aggv = *(const float4*)&agg[(size_t)n * 64 + 4 * fl];

  float4 acc = make_float4(0.f, 0.f, 0.f, 0.f);
  int i = i0 + q;
  for (; i + 4 < end; i += 8) {
    int ra = csr_row[i];
    int rb = csr_row[i + 4];
    ushort4 ua = *(const ushort4*)&t[(size_t)ra * 64 + 4 * fl];
    ushort4 ub = *(const ushort4*)&t[(size_t)rb * 64 + 4 * fl];
    float4 va, vb;
    ((unsigned*)&va)[0] = (unsigned)ua.x << 16; ((unsigned*)&va)[1] = (unsigned)ua.y << 16;
    ((unsigned*)&va)[2] = (unsigned)ua.z << 16; ((unsigned*)&va)[3] = (unsigned)ua.w << 16;
    ((unsigned*)&vb)[0] = (unsigned)ub.x << 16; ((unsigned*)&vb)[1] = (unsigned)ub.y << 16;
    ((unsigned*)&vb)[2] = (unsigned)ub.z << 16; ((unsigned*)&vb)[3] = (unsigned)ub.w << 16;
    acc.x += va.x + vb.x; acc.y += va.y + vb.y;
    acc.z += va.z + vb.z; acc.w += va.w + vb.w;
  }
  for (; i < end; i += 4) {
    int ra = csr_row[i];
    ushort4 ua = *(const ushort4*)&t[(size_t)ra * 64 + 4 * fl];
    float4 va;
    ((unsigned*)&va)[0] = (unsigned)ua.x << 16; ((unsigned*)&va)[1] = (unsigned)ua.y << 16;
    ((unsigned*)&va)[2] = (unsigned)ua.z << 16; ((unsigned*)&va)[3] = (unsigned)ua.w << 16;
    acc.x += va.x; acc.y += va.y; acc.z += va.z; acc.w += va.w;
  }
  acc.x += __shfl_xor(acc.x, 16); acc.y += __shfl_xor(acc.y, 16);
  acc.z += __shfl_xor(acc.z, 16); acc.w += __shfl_xor(acc.w, 16);
  acc.x += __shfl_xor(acc.x, 32); acc.y += __shfl_xor(acc.y, 32);
  acc.z += __shfl_xor(acc.z, 32); acc.w += __shfl_xor(acc.w, 32);
  if (q == 0) {
    rowbuf[w][4 * fl + 0] = fmaxf(aggv.x + dn * acc.x, 0.f);
    rowbuf[w][4 * fl + 1] = fmaxf(aggv.y + dn * acc.y, 0.f);
    rowbuf[w][4 * fl + 2] = fmaxf(aggv.z + dn * acc.z, 0.f);
    rowbuf[w][4 * fl + 3] = fmaxf(aggv.w + dn * acc.w, 0.f);
  }
  // same-wave LDS RAW: compiler inserts lgkmcnt wait; no barrier needed.
  int half = lane >> 5;
  int j = lane & 31;
  float ov = 0.f;
#pragma unroll 8
  for (int k = 32 * half; k < 32 * half + 32; ++k)
    ov = fmaf(rowbuf[w][k], Wo_s[k * 32 + j], ov);
  ov += __shfl_xor(ov, 32);
  if (half == 0) out[(size_t)n * 32 + j] = ov + bo_s[j];
}

extern "C" void kernel_launch(void* const* d_in, const int* in_sizes, int n_in,
                              void* d_out, int out_size, void* d_ws, size_t ws_size,
                              hipStream_t stream) {
  const float* x = (const float*)d_in[0];
  const int* ei = (const int*)d_in[1];
  const float* W_in1 = (const float*)d_in[2];
  const float* W_neigh1 = (const float*)d_in[3];
  const float* bias1 = (const float*)d_in[4];
  const float* W_in2 = (const float*)d_in[5];
  const float* W_neigh2 = (const float*)d_in[6];
  const float* bias2 = (const float*)d_in[7];
  const float* W_out = (const float*)d_in[8];
  const float* b_out = (const float*)d_in[9];
  float* out = (float*)d_out;

  const int N = in_sizes[0] / 64;
  const int E = in_sizes[1] / 2;

  char* ws = (char*)d_ws;
  size_t off = 0;
  auto alloc = [&](size_t bytes) -> void* {
    void* p = ws + off;
    off += (bytes + 255) & ~(size_t)255;
    return p;
  };
  const int sw = (N + 1) & ~1;
  float* dinv = (float*)alloc((size_t)N * 4);
  int* indeg = (int*)alloc((size_t)N * 4);
  int* ptr = (int*)alloc((size_t)N * 4);
  int* bsum = (int*)alloc(1024);
  int* csr_row = (int*)alloc((size_t)E * 4);
  unsigned short* partial = (unsigned short*)alloc((size_t)2 * NCHUNK * sw * 2);
  int* base = (int*)alloc((size_t)NCHUNK * N * 4);
  __hip_bfloat16* t = (__hip_bfloat16*)alloc((size_t)N * 64 * 2);
  __hip_bfloat16* t2 = (__hip_bfloat16*)alloc((size_t)N * 64 * 2);
  float* agg = (float*)alloc((size_t)N * 64 * 4);
  (void)ws_size;

  int range_b = (N + NRANGE_B - 1) / NRANGE_B;  // 6250 <= HIST_B2
  int gN = (N + 255) / 256;
  int gNode = (N + 3) / 4;
  int gFused = (N + 63) / 64;
  int nb = (N + 255) / 256;                     // 196 dinv_scan blocks (256 wide)
  int gemmBlocks = (N + 255) / 256;             // 256 rows per 1024-thread block

  // dispatch 1: layer-1 GEMM (independent of build) fused with full-range hist
  k_hist_gemm1<<<gemmBlocks + 2 * NCHUNK, 1024, 0, stream>>>(
      ei, partial, x, W_neigh1, W_in1, bias1, t, agg, N, E, gemmBlocks);
  k_dinv_scan<<<nb, 256, 0, stream>>>(partial, dinv, indeg, ptr, bsum, N);
  k_base<<<gN, 256, 0, stream>>>(partial, bsum, ptr, base, N, nb);
  k_bin2<<<NRANGE_B * NCHUNK, 1024, 0, stream>>>(ei, base, csr_row, N, E, range_b);

  // fused layer-1 gather + layer-2 dual GEMM (agg in place, t2 prescaled)
  k_gather_gemm2<<<gFused, 1024, 0, stream>>>(csr_row, ptr, indeg, dinv, t, agg,
                                              W_neigh2, W_in2, bias2, t2, N);

  // fused layer-2 gather + output GEMM
  k_gather_out<<<gNode, 256, 0, stream>>>(csr_row, ptr, indeg, dinv, t2, agg,
                                          W_out, b_out, out, N);
}